// Round 1
// baseline (222.636 us; speedup 1.0000x reference)
//
#include <hip/hip_runtime.h>
#include <hip/hip_bf16.h>

// Problem constants (from reference)
#define E_TOTAL 300000
#define N_NODES 50000
#define NDIM    128      // node feature dim (bytes per node in i8 table)
#define KDIM    256      // 2*NDIM = GEMM K
#define HDIM    512      // 2*HIDDEN = GEMM N (both MLP branches fused)
#define BN_EPS  1e-5f
#define NTILES  ((E_TOTAL + 63) / 64)   // 4688 tiles of 64 edges
#define NBLK    512                      // persistent blocks: 2 per CU (LDS fits)
#define NF_BLOCKS 6250                   // 50000*128/4 values / 256 threads
#define LT_MAX  10                       // max tiles per block (ceil(4688/512))
#define A_SCALE 24.0f                    // fixed i8 scale for node feats (clip ~5.3 sigma)

typedef __attribute__((ext_vector_type(4))) int   i32x4;
typedef const __attribute__((address_space(1))) unsigned int* gas1_t;
typedef __attribute__((address_space(3))) unsigned int* las3_t;

__device__ __forceinline__ int q8(float x, float s) {
  float v = fminf(fmaxf(x * s, -127.f), 127.f);
  return (int)rintf(v);
}

// ---- fused prep kernel ----
// blocks [0, NF_BLOCKS): node_feat fp32 -> i8 table (scale A_SCALE)
// blocks [NF_BLOCKS, NF_BLOCKS+32): W1 (BN-folded, roll-fused) -> i8 frag order
//   (operand-symmetric layout, reused as MFMA A-operand), per-column amax scaling.
//   Scales FOLDED into cb2/wp2: cb2[j] = cj/rv_j, wp2[j] = 0.5*W2*rv_j,
//   rv_j = amax_b/(127*A_SCALE) > 0  (relu(x*rv + c) = rv*relu(x + c/rv)).
__global__ void prep_kernel(const float* __restrict__ nf, unsigned char* __restrict__ nfq,
                            const float* __restrict__ W1, const float* __restrict__ b1,
                            const float* __restrict__ gamma, const float* __restrict__ beta,
                            const float* __restrict__ mean, const float* __restrict__ var,
                            const float* __restrict__ W2,
                            unsigned char* __restrict__ Wswz,
                            float* __restrict__ cb2, float* __restrict__ wp2) {
  int b = blockIdx.x;
  int tid = threadIdx.x;
  if (b < NF_BLOCKS) {
    int i = b * 256 + tid;                     // exactly 1.6M float4s
    float4 v = ((const float4*)nf)[i];
    int q0 = q8(v.x, A_SCALE), q1 = q8(v.y, A_SCALE);
    int q2 = q8(v.z, A_SCALE), q3 = q8(v.w, A_SCALE);
    ((unsigned*)nfq)[i] = (q0 & 255) | ((q1 & 255) << 8) | ((q2 & 255) << 16) | ((q3 & 255) << 24);
  } else {
    int ct = b - NF_BLOCKS;                    // 0..31
    __shared__ float amx[16][16];
    __shared__ float sB[16];                   // 127/amax_b per local column
    // pass 1: per-column amax of |W1| (roll is a permutation: same value set)
    {
      int cl = tid >> 4, pt = tid & 15;
      int jj = (ct * 16 + cl) & 255;
      float m = 0.f;
      #pragma unroll
      for (int i = 0; i < 16; i++)
        m = fmaxf(m, fabsf(W1[(pt * 16 + i) * 256 + jj]));
      amx[cl][pt] = m;
    }
    __syncthreads();
    if (tid < 16) {
      int j  = ct * 16 + tid;
      int jj = j & 255;
      float s = gamma[jj] * rsqrtf(var[jj] + BN_EPS);
      float m = 0.f;
      #pragma unroll
      for (int p = 0; p < 16; p++) m = fmaxf(m, amx[tid][p]);
      float amax_b = fmaxf(m * fabsf(s), 1e-20f);
      sB[tid] = 127.f / amax_b;
      float rv = amax_b / (127.f * A_SCALE);
      float cj = b1[jj] * s + beta[jj] - mean[jj] * s;
      cb2[j] = cj / rv;
      wp2[j] = 0.5f * W2[jj] * rv;             // fold the 0.5 average + rv
    }
    __syncthreads();
    // pass 2: quantize into frag order (lane: col=ct*16+l16, k=kt*64+quad*16+..)
    {
      int kt   = tid >> 6;                     // 0..3
      int lane = tid & 63;
      int l16  = lane & 15, quad = lane >> 4;
      int col  = ct * 16 + l16;
      int jj   = col & 255;
      int shift = (col >= 256) ? 16 : 0;
      float s  = gamma[jj] * rsqrtf(var[jj] + BN_EPS);
      float sc = sB[l16];
      unsigned o[4];
      #pragma unroll
      for (int d = 0; d < 4; d++) {
        unsigned pk = 0;
        #pragma unroll
        for (int jb = 0; jb < 4; jb++) {
          int k  = kt * 64 + quad * 16 + d * 4 + jb;
          int ks = (k + shift) & 255;
          int q  = q8(W1[ks * 256 + jj] * s, sc);
          pk |= (unsigned)(q & 255) << (8 * jb);
        }
        o[d] = pk;
      }
      *(uint4*)(Wswz + ((size_t)(ct * 4 + kt) * 64 + lane) * 16) = *(const uint4*)o;
    }
  }
}

// ---- main: persistent, 512 threads = 8 waves, 16x16x64 i8 MFMA, TRANSPOSED:
// W = A-operand (M = columns, bq[4][4] regs), edges = B-operand (N = edges,
// DMA-staged in B-frag order). C layout: edge = l16, col = mt*16+quad*4+r ->
// column reduction is in-lane FMAs + 2 cross-quad shfl stages (no DPP tree).
// LDS = 78848 B <= 81920 -> 2 blocks/CU (16 waves), so one block computes
// while the other sits at its full-drain barrier (m114 overlap).
__global__ __launch_bounds__(512, 4) void edge_mlp_kernel(
    const unsigned char* __restrict__ nfq, const int* __restrict__ eidx,
    const unsigned char* __restrict__ Wswz, const float* __restrict__ cb2,
    const float* __restrict__ wp2, const float* __restrict__ b2,
    float* __restrict__ out) {
  __shared__ unsigned char Ab[4][16 * 1024];   // 64 KB: 16 frags x 64 lanes x 16B
  __shared__ int idxl[LT_MAX * 128];           // 5 KB
  __shared__ float partial[4][8][64];          // 8 KB, ring by tile&3

  const int tid  = threadIdx.x;
  const int w    = tid >> 6;
  const int lane = tid & 63;
  const int l16  = lane & 15;
  const int quad = lane >> 4;
  const int b    = blockIdx.x;
  const int ntl  = (NTILES - b + NBLK - 1) / NBLK;   // 9 or 10

  // ---- W into registers (once): wave w -> col-tiles mt: cols w*64+mt*16.. ----
  const i32x4* Wf = (const i32x4*)Wswz;
  i32x4 bq[4][4];
  #pragma unroll
  for (int mt = 0; mt < 4; mt++)
    #pragma unroll
    for (int kt = 0; kt < 4; kt++)
      bq[mt][kt] = Wf[((w * 4 + mt) * 4 + kt) * 64 + lane];

  // per-lane epilogue constants: col = w*64 + mt*16 + quad*4 + r
  float c2[16], wv[16];
  #pragma unroll
  for (int mt = 0; mt < 4; mt++)
    #pragma unroll
    for (int r = 0; r < 4; r++) {
      int j = w * 64 + mt * 16 + quad * 4 + r;
      c2[mt * 4 + r] = cb2[j];
      wv[mt * 4 + r] = wp2[j];
    }
  const float b2v = b2[0];

  // ---- preload ALL this block's edge indices into LDS ----
  for (int g = tid; g < ntl * 128; g += 512) {
    int lt2 = g >> 7, r = g & 127;
    int half = r >> 6;
    int e = (b + lt2 * NBLK) * 64 + (r & 63);
    if (e >= E_TOTAL) e = E_TOTAL - 1;
    idxl[g] = eidx[half * E_TOTAL + e];
  }
  __syncthreads();

  // staging role (wave-constant): wave w stages frags f = (w&3)*4 + (w>>2)*2 + i
  // nt = w&3 (edge-tile), kt-pair = w>>2: kt in {pair*2, pair*2+1};
  // endpoint half = w>>2 (kt 0,1 -> row node, kt 2,3 -> col node).
  const int snt   = w & 3;
  const int shalf = w >> 2;
  const int sfrag0 = snt * 4 + shalf * 2;

  auto stage = [&](int lt2, int slot) {
    int node = idxl[lt2 * 128 + shalf * 64 + snt * 16 + l16];
    const unsigned char* gbase = nfq + (size_t)node * NDIM + quad * 16;
    // per instr: 4 same-edge lanes (quads) cover one contiguous 64B line
    #pragma unroll
    for (int i = 0; i < 2; i++)
      __builtin_amdgcn_global_load_lds((gas1_t)(gbase + i * 64),
                                       (las3_t)(&Ab[slot][(sfrag0 + i) * 1024]),
                                       16, 0, 0);
  };

  auto combine = [&](int lt2, int le) {
    int e = (b + lt2 * NBLK) * 64 + le;
    if (e < E_TOTAL) {
      float s = 0.f;
      #pragma unroll
      for (int ww = 0; ww < 8; ww++) s += partial[lt2 & 3][ww][le];
      out[e] = 1.0f / (1.0f + __expf(-(s + b2v)));
    }
  };

  auto compute_tile = [&](int lt2) {
    i32x4 acc[4][4] = {};   // [mt][nt]
    const unsigned char* Ap = &Ab[lt2 & 3][lane * 16];
    #pragma unroll
    for (int kt = 0; kt < 4; kt++) {
      i32x4 ef[4];
      #pragma unroll
      for (int nt = 0; nt < 4; nt++)
        ef[nt] = *(const i32x4*)(Ap + (nt * 4 + kt) * 1024);
      #pragma unroll
      for (int nt = 0; nt < 4; nt++)
        #pragma unroll
        for (int mt = 0; mt < 4; mt++)
          acc[mt][nt] = __builtin_amdgcn_mfma_i32_16x16x64_i8(bq[mt][kt], ef[nt], acc[mt][nt], 0, 0, 0);
    }

    // epilogue: per edge-tile nt, sum over my 16 in-lane columns, then 2
    // cross-quad shfl stages. edge = nt*16 + l16.
    float vnt[4];
    #pragma unroll
    for (int nt = 0; nt < 4; nt++) {
      float v = 0.f;
      #pragma unroll
      for (int mt = 0; mt < 4; mt++)
        #pragma unroll
        for (int r = 0; r < 4; r++) {
          float h = (float)acc[mt][nt][r] + c2[mt * 4 + r];
          v = fmaf(fmaxf(h, 0.f), wv[mt * 4 + r], v);
        }
      vnt[nt] = v;
    }
    #pragma unroll
    for (int nt = 0; nt < 4; nt++) vnt[nt] += __shfl_xor(vnt[nt], 16);
    #pragma unroll
    for (int nt = 0; nt < 4; nt++) vnt[nt] += __shfl_xor(vnt[nt], 32);
    if (quad == 0) {
      #pragma unroll
      for (int nt = 0; nt < 4; nt++)
        partial[lt2 & 3][w][nt * 16 + l16] = vnt[nt];
    }
  };

  // ---- prologue: stage tiles 0,1 ----
  stage(0, 0);
  if (1 < ntl) stage(1, 1);

  // ---- main loop: one barrier per PAIR of tiles ----
  for (int lt = 0; lt < ntl; lt += 2) {
    __syncthreads();   // drains own DMAs (issued a full pair ago), syncs partial ring

    int s2 = lt + 2, s3 = lt + 3;
    if (s2 < ntl) stage(s2, s2 & 3);
    if (s3 < ntl) stage(s3, s3 & 3);

    if (lt >= 2) {
      if (tid < 64)       combine(lt - 2, tid);
      else if (tid < 128) combine(lt - 1, tid - 64);
    }

    compute_tile(lt);
    if (lt + 1 < ntl) compute_tile(lt + 1);
  }

  // ---- tail: combine the last pair ----
  __syncthreads();
  if ((ntl & 1) == 0) {
    if (tid < 64)       combine(ntl - 2, tid);
    else if (tid < 128) combine(ntl - 1, tid - 64);
  } else {
    if (tid < 64)       combine(ntl - 1, tid);
  }
}

extern "C" void kernel_launch(void* const* d_in, const int* in_sizes, int n_in,
                              void* d_out, int out_size, void* d_ws, size_t ws_size,
                              hipStream_t stream) {
  const float* node_feat = (const float*)d_in[0];
  const int*   eidx      = (const int*)d_in[1];
  const float* W1        = (const float*)d_in[2];
  const float* b1        = (const float*)d_in[3];
  const float* gamma     = (const float*)d_in[4];
  const float* beta      = (const float*)d_in[5];
  const float* mean      = (const float*)d_in[6];
  const float* var       = (const float*)d_in[7];
  const float* W2        = (const float*)d_in[8];
  const float* b2        = (const float*)d_in[9];
  float* out = (float*)d_out;

  // Workspace: Wswz i8[512*256] (128KB) | cb2 f32[512] | wp2 f32[512]
  //          | nfq i8[50000*128] (6.4MB)
  unsigned char* Wswz = (unsigned char*)d_ws;
  float* cb2 = (float*)((char*)d_ws + (size_t)HDIM * KDIM);
  float* wp2 = cb2 + HDIM;
  unsigned char* nfq = (unsigned char*)(wp2 + HDIM);

  prep_kernel<<<NF_BLOCKS + 32, 256, 0, stream>>>(node_feat, nfq, W1, b1, gamma, beta,
                                                  mean, var, W2, Wswz, cb2, wp2);

  edge_mlp_kernel<<<NBLK, 512, 0, stream>>>(nfq, eidx, Wswz, cb2, wp2, b2, out);
}

// Round 2
// 191.144 us; speedup vs baseline: 1.1648x; 1.1648x over previous
//
#include <hip/hip_runtime.h>
#include <hip/hip_bf16.h>

// Problem constants (from reference)
#define E_TOTAL 300000
#define N_NODES 50000
#define NDIM    128      // node feature dim (bytes per node in i8 table)
#define KDIM    256      // 2*NDIM = GEMM K
#define HDIM    512      // 2*HIDDEN = GEMM N (both MLP branches fused)
#define BN_EPS  1e-5f
#define NTILES  ((E_TOTAL + 63) / 64)   // 4688 tiles of 64 edges
#define NBLK    512                      // persistent blocks: 2 per CU (LDS+regs fit)
#define NF_BLOCKS 6250                   // 50000*128/4 values / 256 threads
#define LT_MAX  10                       // max tiles per block (ceil(4688/512))
#define A_SCALE 24.0f                    // fixed i8 scale for node feats (clip ~5.3 sigma)

typedef __attribute__((ext_vector_type(4))) int   i32x4;
typedef const __attribute__((address_space(1))) unsigned int* gas1_t;
typedef __attribute__((address_space(3))) unsigned int* las3_t;

__device__ __forceinline__ int q8(float x, float s) {
  float v = fminf(fmaxf(x * s, -127.f), 127.f);
  return (int)rintf(v);
}

// ---- fused prep kernel ----
// blocks [0, NF_BLOCKS): node_feat fp32 -> i8 table (scale A_SCALE)
// blocks [NF_BLOCKS, NF_BLOCKS+32): W1 (BN-folded, roll-fused) -> i8 frag order
//   (operand-symmetric layout, reused as MFMA A-operand), per-column amax scaling.
//   Scales FOLDED into cb2/wp2: cb2[j] = cj/rv_j, wp2[j] = 0.5*W2*rv_j,
//   rv_j = amax_b/(127*A_SCALE) > 0  (relu(x*rv + c) = rv*relu(x + c/rv)).
__global__ void prep_kernel(const float* __restrict__ nf, unsigned char* __restrict__ nfq,
                            const float* __restrict__ W1, const float* __restrict__ b1,
                            const float* __restrict__ gamma, const float* __restrict__ beta,
                            const float* __restrict__ mean, const float* __restrict__ var,
                            const float* __restrict__ W2,
                            unsigned char* __restrict__ Wswz,
                            float* __restrict__ cb2, float* __restrict__ wp2) {
  int b = blockIdx.x;
  int tid = threadIdx.x;
  if (b < NF_BLOCKS) {
    int i = b * 256 + tid;                     // exactly 1.6M float4s
    float4 v = ((const float4*)nf)[i];
    int q0 = q8(v.x, A_SCALE), q1 = q8(v.y, A_SCALE);
    int q2 = q8(v.z, A_SCALE), q3 = q8(v.w, A_SCALE);
    ((unsigned*)nfq)[i] = (q0 & 255) | ((q1 & 255) << 8) | ((q2 & 255) << 16) | ((q3 & 255) << 24);
  } else {
    int ct = b - NF_BLOCKS;                    // 0..31
    __shared__ float amx[16][16];
    __shared__ float sB[16];                   // 127/amax_b per local column
    // pass 1: per-column amax of |W1| (roll is a permutation: same value set)
    {
      int cl = tid >> 4, pt = tid & 15;
      int jj = (ct * 16 + cl) & 255;
      float m = 0.f;
      #pragma unroll
      for (int i = 0; i < 16; i++)
        m = fmaxf(m, fabsf(W1[(pt * 16 + i) * 256 + jj]));
      amx[cl][pt] = m;
    }
    __syncthreads();
    if (tid < 16) {
      int j  = ct * 16 + tid;
      int jj = j & 255;
      float s = gamma[jj] * rsqrtf(var[jj] + BN_EPS);
      float m = 0.f;
      #pragma unroll
      for (int p = 0; p < 16; p++) m = fmaxf(m, amx[tid][p]);
      float amax_b = fmaxf(m * fabsf(s), 1e-20f);
      sB[tid] = 127.f / amax_b;
      float rv = amax_b / (127.f * A_SCALE);
      float cj = b1[jj] * s + beta[jj] - mean[jj] * s;
      cb2[j] = cj / rv;
      wp2[j] = 0.5f * W2[jj] * rv;             // fold the 0.5 average + rv
    }
    __syncthreads();
    // pass 2: quantize into frag order (lane: col=ct*16+l16, k=kt*64+quad*16+..)
    {
      int kt   = tid >> 6;                     // 0..3
      int lane = tid & 63;
      int l16  = lane & 15, quad = lane >> 4;
      int col  = ct * 16 + l16;
      int jj   = col & 255;
      int shift = (col >= 256) ? 16 : 0;
      float s  = gamma[jj] * rsqrtf(var[jj] + BN_EPS);
      float sc = sB[l16];
      unsigned o[4];
      #pragma unroll
      for (int d = 0; d < 4; d++) {
        unsigned pk = 0;
        #pragma unroll
        for (int jb = 0; jb < 4; jb++) {
          int k  = kt * 64 + quad * 16 + d * 4 + jb;
          int ks = (k + shift) & 255;
          int q  = q8(W1[ks * 256 + jj] * s, sc);
          pk |= (unsigned)(q & 255) << (8 * jb);
        }
        o[d] = pk;
      }
      *(uint4*)(Wswz + ((size_t)(ct * 4 + kt) * 64 + lane) * 16) = *(const uint4*)o;
    }
  }
}

// ---- main: persistent, 512 threads = 8 waves, 16x16x64 i8 MFMA, TRANSPOSED:
// W = A-operand (M = columns, bq[4][4] regs), edges = B-operand (N = edges,
// DMA-staged in B-frag order). C layout: edge = l16, col = mt*16+quad*4+r ->
// column reduction is in-lane FMAs + 2 cross-quad shfl stages (no DPP tree).
//
// Occupancy design (round-2 fix): 2 blocks/CU requires BOTH
//   LDS <= 81920  (Ab 64K + idxl-u16 2.5K + partial 8K + c2l/wvl 4K = 80384)
//   regs <= 128/wave (bq 64 + acc[4][2] 32 + ef 8 + transients ~16)
// -> epilogue consts live in LDS, compute split by nt-halves (acc 64 -> 32).
__global__ __launch_bounds__(512, 4) void edge_mlp_kernel(
    const unsigned char* __restrict__ nfq, const int* __restrict__ eidx,
    const unsigned char* __restrict__ Wswz, const float* __restrict__ cb2,
    const float* __restrict__ wp2, const float* __restrict__ b2,
    float* __restrict__ out) {
  __shared__ unsigned char Ab[4][16 * 1024];   // 64 KB: 16 frags x 64 lanes x 16B
  __shared__ unsigned short idxl[LT_MAX * 128];// 2.5 KB (node ids < 65536)
  __shared__ float partial[4][8][64];          // 8 KB, ring by tile&3
  __shared__ float c2l[HDIM];                  // 2 KB epilogue consts
  __shared__ float wvl[HDIM];                  // 2 KB

  const int tid  = threadIdx.x;
  const int w    = tid >> 6;
  const int lane = tid & 63;
  const int l16  = lane & 15;
  const int quad = lane >> 4;
  const int b    = blockIdx.x;
  const int ntl  = (NTILES - b + NBLK - 1) / NBLK;   // 9 or 10

  // ---- W into registers (once): wave w -> col-tiles mt: cols w*64+mt*16.. ----
  const i32x4* Wf = (const i32x4*)Wswz;
  i32x4 bq[4][4];
  #pragma unroll
  for (int mt = 0; mt < 4; mt++)
    #pragma unroll
    for (int kt = 0; kt < 4; kt++)
      bq[mt][kt] = Wf[((w * 4 + mt) * 4 + kt) * 64 + lane];

  // epilogue consts -> LDS (1 value per thread)
  c2l[tid] = cb2[tid];
  wvl[tid] = wp2[tid];
  const float b2v = b2[0];

  // ---- preload ALL this block's edge indices into LDS (u16) ----
  for (int g = tid; g < ntl * 128; g += 512) {
    int lt2 = g >> 7, r = g & 127;
    int half = r >> 6;
    int e = (b + lt2 * NBLK) * 64 + (r & 63);
    if (e >= E_TOTAL) e = E_TOTAL - 1;
    idxl[g] = (unsigned short)eidx[half * E_TOTAL + e];
  }
  __syncthreads();

  // staging role (wave-constant): wave w stages frags f = (w&3)*4 + (w>>2)*2 + i
  // nt = w&3 (edge-tile), kt-pair = w>>2: kt in {pair*2, pair*2+1};
  // endpoint half = w>>2 (kt 0,1 -> row node, kt 2,3 -> col node).
  const int snt   = w & 3;
  const int shalf = w >> 2;
  const int sfrag0 = snt * 4 + shalf * 2;

  auto stage = [&](int lt2, int slot) {
    int node = idxl[lt2 * 128 + shalf * 64 + snt * 16 + l16];
    const unsigned char* gbase = nfq + (size_t)node * NDIM + quad * 16;
    // per instr: 4 same-edge lanes (quads) cover one contiguous 64B line
    #pragma unroll
    for (int i = 0; i < 2; i++)
      __builtin_amdgcn_global_load_lds((gas1_t)(gbase + i * 64),
                                       (las3_t)(&Ab[slot][(sfrag0 + i) * 1024]),
                                       16, 0, 0);
  };

  auto combine = [&](int lt2, int le) {
    int e = (b + lt2 * NBLK) * 64 + le;
    if (e < E_TOTAL) {
      float s = 0.f;
      #pragma unroll
      for (int ww = 0; ww < 8; ww++) s += partial[lt2 & 3][ww][le];
      out[e] = 1.0f / (1.0f + __expf(-(s + b2v)));
    }
  };

  auto compute_tile = [&](int lt2) {
    const unsigned char* Ap = &Ab[lt2 & 3][lane * 16];
    // nt-halves: halves peak acc pressure (64 -> 32 regs)
    #pragma unroll
    for (int h = 0; h < 2; h++) {
      i32x4 acc[4][2] = {};   // [mt][n]
      #pragma unroll
      for (int kt = 0; kt < 4; kt++) {
        i32x4 ef[2];
        #pragma unroll
        for (int n = 0; n < 2; n++)
          ef[n] = *(const i32x4*)(Ap + ((h * 2 + n) * 4 + kt) * 1024);
        #pragma unroll
        for (int n = 0; n < 2; n++)
          #pragma unroll
          for (int mt = 0; mt < 4; mt++)
            acc[mt][n] = __builtin_amdgcn_mfma_i32_16x16x64_i8(bq[mt][kt], ef[n], acc[mt][n], 0, 0, 0);
      }

      // epilogue: per edge-subtile n, sum over my 16 in-lane columns, then 2
      // cross-quad shfl stages. edge = (h*2+n)*16 + l16.
      float v0 = 0.f, v1 = 0.f;
      #pragma unroll
      for (int mt = 0; mt < 4; mt++) {
        int j = w * 64 + mt * 16 + quad * 4;
        float4 cc = *(const float4*)&c2l[j];
        float4 wv = *(const float4*)&wvl[j];
        v0 = fmaf(fmaxf((float)acc[mt][0][0] + cc.x, 0.f), wv.x, v0);
        v0 = fmaf(fmaxf((float)acc[mt][0][1] + cc.y, 0.f), wv.y, v0);
        v0 = fmaf(fmaxf((float)acc[mt][0][2] + cc.z, 0.f), wv.z, v0);
        v0 = fmaf(fmaxf((float)acc[mt][0][3] + cc.w, 0.f), wv.w, v0);
        v1 = fmaf(fmaxf((float)acc[mt][1][0] + cc.x, 0.f), wv.x, v1);
        v1 = fmaf(fmaxf((float)acc[mt][1][1] + cc.y, 0.f), wv.y, v1);
        v1 = fmaf(fmaxf((float)acc[mt][1][2] + cc.z, 0.f), wv.z, v1);
        v1 = fmaf(fmaxf((float)acc[mt][1][3] + cc.w, 0.f), wv.w, v1);
      }
      v0 += __shfl_xor(v0, 16); v0 += __shfl_xor(v0, 32);
      v1 += __shfl_xor(v1, 16); v1 += __shfl_xor(v1, 32);
      if (quad == 0) {
        partial[lt2 & 3][w][(h * 2 + 0) * 16 + l16] = v0;
        partial[lt2 & 3][w][(h * 2 + 1) * 16 + l16] = v1;
      }
    }
  };

  // ---- prologue: stage tiles 0,1 ----
  stage(0, 0);
  if (1 < ntl) stage(1, 1);

  // ---- main loop: one barrier per PAIR of tiles ----
  for (int lt = 0; lt < ntl; lt += 2) {
    __syncthreads();   // drains own DMAs (issued a full pair ago), syncs partial ring

    int s2 = lt + 2, s3 = lt + 3;
    if (s2 < ntl) stage(s2, s2 & 3);
    if (s3 < ntl) stage(s3, s3 & 3);

    if (lt >= 2) {
      if (tid < 64)       combine(lt - 2, tid);
      else if (tid < 128) combine(lt - 1, tid - 64);
    }

    compute_tile(lt);
    if (lt + 1 < ntl) compute_tile(lt + 1);
  }

  // ---- tail: combine the last pair ----
  __syncthreads();
  if ((ntl & 1) == 0) {
    if (tid < 64)       combine(ntl - 2, tid);
    else if (tid < 128) combine(ntl - 1, tid - 64);
  } else {
    if (tid < 64)       combine(ntl - 1, tid);
  }
}

extern "C" void kernel_launch(void* const* d_in, const int* in_sizes, int n_in,
                              void* d_out, int out_size, void* d_ws, size_t ws_size,
                              hipStream_t stream) {
  const float* node_feat = (const float*)d_in[0];
  const int*   eidx      = (const int*)d_in[1];
  const float* W1        = (const float*)d_in[2];
  const float* b1        = (const float*)d_in[3];
  const float* gamma     = (const float*)d_in[4];
  const float* beta      = (const float*)d_in[5];
  const float* mean      = (const float*)d_in[6];
  const float* var       = (const float*)d_in[7];
  const float* W2        = (const float*)d_in[8];
  const float* b2        = (const float*)d_in[9];
  float* out = (float*)d_out;

  // Workspace: Wswz i8[512*256] (128KB) | cb2 f32[512] | wp2 f32[512]
  //          | nfq i8[50000*128] (6.4MB)
  unsigned char* Wswz = (unsigned char*)d_ws;
  float* cb2 = (float*)((char*)d_ws + (size_t)HDIM * KDIM);
  float* wp2 = cb2 + HDIM;
  unsigned char* nfq = (unsigned char*)(wp2 + HDIM);

  prep_kernel<<<NF_BLOCKS + 32, 256, 0, stream>>>(node_feat, nfq, W1, b1, gamma, beta,
                                                  mean, var, W2, Wswz, cb2, wp2);

  edge_mlp_kernel<<<NBLK, 512, 0, stream>>>(nfq, eidx, Wswz, cb2, wp2, b2, out);
}

// Round 3
// 135.271 us; speedup vs baseline: 1.6459x; 1.4131x over previous
//
#include <hip/hip_runtime.h>
#include <hip/hip_bf16.h>

// Problem constants (from reference)
#define E_TOTAL 300000
#define N_NODES 50000
#define NDIM    128      // node feature dim (bytes per node in i8 table)
#define KDIM    256      // 2*NDIM = GEMM K
#define HDIM    512      // 2*HIDDEN = GEMM N (both MLP branches fused)
#define BN_EPS  1e-5f
#define NTILES  ((E_TOTAL + 63) / 64)   // 4688 tiles of 64 edges
#define NBLK    512                      // 256 tile-lanes x 2 column-halves
#define TLANES  256                      // tile stride (blocks per column-half)
#define NF_BLOCKS 6250                   // 50000*128/4 values / 256 threads
#define LT_MAX  19                       // max tiles per block (ceil(4688/256))
#define A_SCALE 24.0f                    // fixed i8 scale for node feats (clip ~5.3 sigma)

typedef __attribute__((ext_vector_type(4))) int   i32x4;
typedef const __attribute__((address_space(1))) unsigned int* gas1_t;
typedef __attribute__((address_space(3))) unsigned int* las3_t;

__device__ __forceinline__ int q8(float x, float s) {
  float v = fminf(fmaxf(x * s, -127.f), 127.f);
  return (int)rintf(v);
}

// ---- fused prep kernel ----
// blocks [0, NF_BLOCKS): node_feat fp32 -> i8 table (scale A_SCALE)
// blocks [NF_BLOCKS, NF_BLOCKS+32): W1 (BN-folded, roll-fused) -> i8 frag order
//   (operand-symmetric layout, reused as MFMA A-operand), per-column amax scaling.
//   Scales FOLDED into cb2/wp2: cb2[j] = cj/rv_j, wp2[j] = 0.5*W2*rv_j,
//   rv_j = amax_b/(127*A_SCALE) > 0  (relu(x*rv + c) = rv*relu(x + c/rv)).
__global__ void prep_kernel(const float* __restrict__ nf, unsigned char* __restrict__ nfq,
                            const float* __restrict__ W1, const float* __restrict__ b1,
                            const float* __restrict__ gamma, const float* __restrict__ beta,
                            const float* __restrict__ mean, const float* __restrict__ var,
                            const float* __restrict__ W2,
                            unsigned char* __restrict__ Wswz,
                            float* __restrict__ cb2, float* __restrict__ wp2) {
  int b = blockIdx.x;
  int tid = threadIdx.x;
  if (b < NF_BLOCKS) {
    int i = b * 256 + tid;                     // exactly 1.6M float4s
    float4 v = ((const float4*)nf)[i];
    int q0 = q8(v.x, A_SCALE), q1 = q8(v.y, A_SCALE);
    int q2 = q8(v.z, A_SCALE), q3 = q8(v.w, A_SCALE);
    ((unsigned*)nfq)[i] = (q0 & 255) | ((q1 & 255) << 8) | ((q2 & 255) << 16) | ((q3 & 255) << 24);
  } else {
    int ct = b - NF_BLOCKS;                    // 0..31
    __shared__ float amx[16][16];
    __shared__ float sB[16];                   // 127/amax_b per local column
    // pass 1: per-column amax of |W1| (roll is a permutation: same value set)
    {
      int cl = tid >> 4, pt = tid & 15;
      int jj = (ct * 16 + cl) & 255;
      float m = 0.f;
      #pragma unroll
      for (int i = 0; i < 16; i++)
        m = fmaxf(m, fabsf(W1[(pt * 16 + i) * 256 + jj]));
      amx[cl][pt] = m;
    }
    __syncthreads();
    if (tid < 16) {
      int j  = ct * 16 + tid;
      int jj = j & 255;
      float s = gamma[jj] * rsqrtf(var[jj] + BN_EPS);
      float m = 0.f;
      #pragma unroll
      for (int p = 0; p < 16; p++) m = fmaxf(m, amx[tid][p]);
      float amax_b = fmaxf(m * fabsf(s), 1e-20f);
      sB[tid] = 127.f / amax_b;
      float rv = amax_b / (127.f * A_SCALE);
      float cj = b1[jj] * s + beta[jj] - mean[jj] * s;
      cb2[j] = cj / rv;
      wp2[j] = 0.5f * W2[jj] * rv;             // fold the 0.5 average + rv
    }
    __syncthreads();
    // pass 2: quantize into frag order (lane: col=ct*16+l16, k=kt*64+quad*16+..)
    {
      int kt   = tid >> 6;                     // 0..3
      int lane = tid & 63;
      int l16  = lane & 15, quad = lane >> 4;
      int col  = ct * 16 + l16;
      int jj   = col & 255;
      int shift = (col >= 256) ? 16 : 0;
      float s  = gamma[jj] * rsqrtf(var[jj] + BN_EPS);
      float sc = sB[l16];
      unsigned o[4];
      #pragma unroll
      for (int d = 0; d < 4; d++) {
        unsigned pk = 0;
        #pragma unroll
        for (int jb = 0; jb < 4; jb++) {
          int k  = kt * 64 + quad * 16 + d * 4 + jb;
          int ks = (k + shift) & 255;
          int q  = q8(W1[ks * 256 + jj] * s, sc);
          pk |= (unsigned)(q & 255) << (8 * jb);
        }
        o[d] = pk;
      }
      *(uint4*)(Wswz + ((size_t)(ct * 4 + kt) * 64 + lane) * 16) = *(const uint4*)o;
    }
  }
}

// ---- main: persistent, 512 threads = 8 waves, 16x16x64 i8 MFMA, TRANSPOSED:
// W = A-operand (M = columns), edges = B-operand (N = edges, DMA-staged in
// B-frag order). COLUMN-SPLIT blocks (round-3): block b owns columns
// [ph*256, ph*256+256) where ph = b&1; tiles tb = b>>1, stride TLANES.
// Per wave: 32 cols (2 mt) -> bq[2][4] = 32 regs, acc[2][4] = 32 regs;
// peak ~105 unified regs <= 128 -> honest 4 waves/SIMD (2 blocks/CU).
// LDS = Ab 64K + idxl 4.75K + partial 8K + c2l/wvl 2K = 80640 <= 81920.
// Cross-half sum + sigmoid happens in sigmoid_kernel (plain partial stores).
__global__ __launch_bounds__(512, 4) void edge_mlp_kernel(
    const unsigned char* __restrict__ nfq, const int* __restrict__ eidx,
    const unsigned char* __restrict__ Wswz, const float* __restrict__ cb2,
    const float* __restrict__ wp2, float* __restrict__ part) {
  __shared__ unsigned char Ab[4][16 * 1024];   // 64 KB: 16 frags x 64 lanes x 16B
  __shared__ unsigned short idxl[LT_MAX * 128];// 4.75 KB (node ids < 65536)
  __shared__ float partial[4][8][64];          // 8 KB, ring by tile&3
  __shared__ float c2l[256];                   // 1 KB epilogue consts (this half)
  __shared__ float wvl[256];                   // 1 KB

  const int tid  = threadIdx.x;
  const int w    = tid >> 6;
  const int lane = tid & 63;
  const int l16  = lane & 15;
  const int quad = lane >> 4;
  const int b    = blockIdx.x;
  const int ph   = b & 1;                      // column half
  const int tb   = b >> 1;                     // tile lane
  const int ntl  = (NTILES - tb + TLANES - 1) / TLANES;   // 18 or 19

  // ---- W into registers (once): wave w -> col-tiles ct = ph*16 + w*2 + mt ----
  const i32x4* Wf = (const i32x4*)Wswz;
  i32x4 bq[2][4];
  #pragma unroll
  for (int mt = 0; mt < 2; mt++)
    #pragma unroll
    for (int kt = 0; kt < 4; kt++)
      bq[mt][kt] = Wf[(((ph * 16 + w * 2 + mt) * 4) + kt) * 64 + lane];

  // epilogue consts -> LDS (this half's 256 columns)
  if (tid < 256) c2l[tid] = cb2[ph * 256 + tid];
  else           wvl[tid - 256] = wp2[ph * 256 + tid - 256];

  // ---- preload ALL this block's edge indices into LDS (u16) ----
  for (int g = tid; g < ntl * 128; g += 512) {
    int lt2 = g >> 7, r = g & 127;
    int half = r >> 6;
    int e = (tb + lt2 * TLANES) * 64 + (r & 63);
    if (e >= E_TOTAL) e = E_TOTAL - 1;
    idxl[g] = (unsigned short)eidx[half * E_TOTAL + e];
  }
  __syncthreads();

  // staging role (wave-constant): wave w stages frags f = (w&3)*4 + (w>>2)*2 + i
  // nt = w&3 (edge-tile), kt-pair = w>>2: kt in {pair*2, pair*2+1};
  // endpoint half = w>>2 (kt 0,1 -> row node, kt 2,3 -> col node).
  const int snt   = w & 3;
  const int shalf = w >> 2;
  const int sfrag0 = snt * 4 + shalf * 2;

  auto stage = [&](int lt2, int slot) {
    int node = idxl[lt2 * 128 + shalf * 64 + snt * 16 + l16];
    const unsigned char* gbase = nfq + (size_t)node * NDIM + quad * 16;
    // per instr: 4 same-edge lanes (quads) cover one contiguous 64B line
    #pragma unroll
    for (int i = 0; i < 2; i++)
      __builtin_amdgcn_global_load_lds((gas1_t)(gbase + i * 64),
                                       (las3_t)(&Ab[slot][(sfrag0 + i) * 1024]),
                                       16, 0, 0);
  };

  auto combine = [&](int lt2, int le) {
    int e = (tb + lt2 * TLANES) * 64 + le;
    if (e < E_TOTAL) {
      float s = 0.f;
      #pragma unroll
      for (int ww = 0; ww < 8; ww++) s += partial[lt2 & 3][ww][le];
      part[ph * E_TOTAL + e] = s;              // plain store; sigmoid kernel sums halves
    }
  };

  auto compute_tile = [&](int lt2) {
    const unsigned char* Ap = &Ab[lt2 & 3][lane * 16];
    i32x4 acc[2][4] = {};   // [mt][nt]
    #pragma unroll
    for (int kt = 0; kt < 4; kt++) {
      i32x4 ef[4];
      #pragma unroll
      for (int nt = 0; nt < 4; nt++)
        ef[nt] = *(const i32x4*)(Ap + (nt * 4 + kt) * 1024);
      #pragma unroll
      for (int nt = 0; nt < 4; nt++)
        #pragma unroll
        for (int mt = 0; mt < 2; mt++)
          acc[mt][nt] = __builtin_amdgcn_mfma_i32_16x16x64_i8(bq[mt][kt], ef[nt], acc[mt][nt], 0, 0, 0);
    }

    // epilogue: per edge-tile nt, sum over my 8 in-lane columns, then 2
    // cross-quad shfl stages. edge = nt*16 + l16.
    float vnt[4];
    #pragma unroll
    for (int nt = 0; nt < 4; nt++) {
      float v = 0.f;
      #pragma unroll
      for (int mt = 0; mt < 2; mt++) {
        int j = w * 32 + mt * 16 + quad * 4;
        float4 cc = *(const float4*)&c2l[j];
        float4 wv = *(const float4*)&wvl[j];
        v = fmaf(fmaxf((float)acc[mt][nt][0] + cc.x, 0.f), wv.x, v);
        v = fmaf(fmaxf((float)acc[mt][nt][1] + cc.y, 0.f), wv.y, v);
        v = fmaf(fmaxf((float)acc[mt][nt][2] + cc.z, 0.f), wv.z, v);
        v = fmaf(fmaxf((float)acc[mt][nt][3] + cc.w, 0.f), wv.w, v);
      }
      vnt[nt] = v;
    }
    #pragma unroll
    for (int nt = 0; nt < 4; nt++) vnt[nt] += __shfl_xor(vnt[nt], 16);
    #pragma unroll
    for (int nt = 0; nt < 4; nt++) vnt[nt] += __shfl_xor(vnt[nt], 32);
    if (quad == 0) {
      #pragma unroll
      for (int nt = 0; nt < 4; nt++)
        partial[lt2 & 3][w][nt * 16 + l16] = vnt[nt];
    }
  };

  // ---- prologue: stage tiles 0,1 ----
  stage(0, 0);
  if (1 < ntl) stage(1, 1);

  // ---- main loop: one barrier per PAIR of tiles ----
  for (int lt = 0; lt < ntl; lt += 2) {
    __syncthreads();   // drains own DMAs (issued a full pair ago), syncs partial ring

    int s2 = lt + 2, s3 = lt + 3;
    if (s2 < ntl) stage(s2, s2 & 3);
    if (s3 < ntl) stage(s3, s3 & 3);

    if (lt >= 2) {
      if (tid < 64)       combine(lt - 2, tid);
      else if (tid < 128) combine(lt - 1, tid - 64);
    }

    compute_tile(lt);
    if (lt + 1 < ntl) compute_tile(lt + 1);
  }

  // ---- tail: combine the last pair ----
  __syncthreads();
  if ((ntl & 1) == 0) {
    if (tid < 64)       combine(ntl - 2, tid);
    else if (tid < 128) combine(ntl - 1, tid - 64);
  } else {
    if (tid < 64)       combine(ntl - 1, tid);
  }
}

// ---- final: out = sigmoid(part0 + part1 + b2), vectorized float4 ----
__global__ void sigmoid_kernel(const float* __restrict__ part,
                               const float* __restrict__ b2,
                               float* __restrict__ out) {
  int i = blockIdx.x * 256 + threadIdx.x;      // float4 index, 75000 total
  if (i < E_TOTAL / 4) {
    float4 a = ((const float4*)part)[i];
    float4 c = ((const float4*)(part + E_TOTAL))[i];
    float bb = b2[0];
    float4 o;
    o.x = 1.0f / (1.0f + __expf(-(a.x + c.x + bb)));
    o.y = 1.0f / (1.0f + __expf(-(a.y + c.y + bb)));
    o.z = 1.0f / (1.0f + __expf(-(a.z + c.z + bb)));
    o.w = 1.0f / (1.0f + __expf(-(a.w + c.w + bb)));
    ((float4*)out)[i] = o;
  }
}

extern "C" void kernel_launch(void* const* d_in, const int* in_sizes, int n_in,
                              void* d_out, int out_size, void* d_ws, size_t ws_size,
                              hipStream_t stream) {
  const float* node_feat = (const float*)d_in[0];
  const int*   eidx      = (const int*)d_in[1];
  const float* W1        = (const float*)d_in[2];
  const float* b1        = (const float*)d_in[3];
  const float* gamma     = (const float*)d_in[4];
  const float* beta      = (const float*)d_in[5];
  const float* mean      = (const float*)d_in[6];
  const float* var       = (const float*)d_in[7];
  const float* W2        = (const float*)d_in[8];
  const float* b2        = (const float*)d_in[9];
  float* out = (float*)d_out;

  // Workspace: Wswz i8[512*256] (128KB) | cb2 f32[512] | wp2 f32[512]
  //          | nfq i8[50000*128] (6.4MB) | part f32[2*300000] (2.4MB)
  unsigned char* Wswz = (unsigned char*)d_ws;
  float* cb2 = (float*)((char*)d_ws + (size_t)HDIM * KDIM);
  float* wp2 = cb2 + HDIM;
  unsigned char* nfq = (unsigned char*)(wp2 + HDIM);
  float* part = (float*)(nfq + (size_t)N_NODES * NDIM);

  prep_kernel<<<NF_BLOCKS + 32, 256, 0, stream>>>(node_feat, nfq, W1, b1, gamma, beta,
                                                  mean, var, W2, Wswz, cb2, wp2);

  edge_mlp_kernel<<<NBLK, 512, 0, stream>>>(nfq, eidx, Wswz, cb2, wp2, part);

  sigmoid_kernel<<<(E_TOTAL / 4 + 255) / 256, 256, 0, stream>>>(part, b2, out);
}